// Round 2
// baseline (561.675 us; speedup 1.0000x reference)
//
#include <hip/hip_runtime.h>

#define MNK (128*128*128)

__device__ __forceinline__ float wave_sum(float v) {
  v += __shfl_xor(v, 32, 64);
  v += __shfl_xor(v, 16, 64);
  v += __shfl_xor(v, 8, 64);
  v += __shfl_xor(v, 4, 64);
  v += __shfl_xor(v, 2, 64);
  v += __shfl_xor(v, 1, 64);
  return v;
}

// One workgroup per 8^3 spatial block, 256 threads (4 waves).
// Thread t -> p = t>>5 (0..7), q = (t>>2)&7, r0 = 2*(t&3): a (1,1,2)
// micro-tile => 54 weight floats/thread, guaranteed register-resident.
// Window double-buffered in LDS: 1 barrier per inner iteration.
__global__ __launch_bounds__(256, 4) void gridnet_kernel(
    const float* __restrict__ weight, const float* __restrict__ bias,
    const float* __restrict__ rscale, const float* __restrict__ x,
    float* __restrict__ out) {
  __shared__ float Wl[2][1200];   // [buf][(wp*10+wq)*12 + wk], rows padded 10->12
  __shared__ float red[32];       // [0..15]: iter partials (2 parities), [16..31]: init

  const int t = threadIdx.x;
  const int r0 = (t & 3) * 2;
  const int q = (t >> 2) & 7;
  const int p = t >> 5;
  const int wv_ = t >> 6;

  // Invert the round-robin workgroup->XCD map so k-adjacent blocks (which
  // share weight/x cache lines) land on the same XCD's L2.
  const int H = blockIdx.x;
  const int L = (H & 7) * 512 + (H >> 3);
  const int bm = L >> 8, bn = (L >> 4) & 15, bk = L & 15;
  const int gm0 = bm * 8, gn0 = bn * 8, gk0 = bk * 8;
  const int baseg = ((gm0 + p) * 128 + (gn0 + q)) * 128 + (gk0 + r0);

  // 27 weights per output; wA -> k=r0, wB -> k=r0+1. Flat constant-indexed.
  float wA[27], wB[27];
  float SA = 0.f, SB = 0.f;
#pragma unroll
  for (int o = 0; o < 27; ++o) {
    float2 wv = *(const float2*)(weight + o * MNK + baseg);
    wA[o] = wv.x; wB[o] = wv.y;
    SA += wv.x; SB += wv.y;
  }
  const float2 bv = *(const float2*)(bias + baseg);
  const float2 rv = *(const float2*)(rscale + baseg);

  for (int b = 0; b < 4; ++b) {
    __syncthreads();  // prior batch finished reading Wl
    // ---- load 10^3 halo window (zero-padded at grid edges) into both bufs ----
    float sA = 0.f, sQ = 0.f, sH = 0.f, sHq = 0.f;
    for (int idx = t; idx < 1000; idx += 256) {
      int wp = idx / 100;
      int rem = idx - wp * 100;
      int wq = rem / 10;
      int wk = rem - wq * 10;
      int gm = gm0 - 1 + wp, gn = gn0 - 1 + wq, gk = gk0 - 1 + wk;
      float v = 0.f;
      if ((unsigned)gm < 128u && (unsigned)gn < 128u && (unsigned)gk < 128u)
        v = x[((b * 128 + gm) * 128 + gn) * 128 + gk];
      const int ai = (wp * 10 + wq) * 12 + wk;
      Wl[0][ai] = v;
      Wl[1][ai] = v;
      sA += v; sQ += v * v;
      // halo shell is never updated: fold its stats once per batch
      if (wp == 0 || wp == 9 || wq == 0 || wq == 9 || wk == 0 || wk == 9) {
        sH += v; sHq += v * v;
      }
    }
    sA = wave_sum(sA); sQ = wave_sum(sQ);
    sH = wave_sum(sH); sHq = wave_sum(sHq);
    if ((t & 63) == 0) {
      red[16 + wv_ * 4 + 0] = sA; red[16 + wv_ * 4 + 1] = sQ;
      red[16 + wv_ * 4 + 2] = sH; red[16 + wv_ * 4 + 3] = sHq;
    }
    __syncthreads();
    const float tS = red[16] + red[20] + red[24] + red[28];
    const float tQ = red[17] + red[21] + red[25] + red[29];
    const float hS = red[18] + red[22] + red[26] + red[30];
    const float hQ = red[19] + red[23] + red[27] + red[31];

    float a0 = Wl[0][((p + 1) * 10 + q + 1) * 12 + r0 + 1];
    float a1 = Wl[0][((p + 1) * 10 + q + 1) * 12 + r0 + 2];

    float mu = tS * 1e-3f;
    float var = tQ * 1e-3f - mu * mu;
    float inv = __builtin_amdgcn_rsqf(var + 1e-5f);

    int cur = 0;
    for (int it = 0; it < 8; ++it) {
      // ---- 3^3 locally-connected conv on RAW acts (layernorm folded) ----
      const float* Wc = Wl[cur];
      float acc0 = 0.f, acc1 = 0.f;
#pragma unroll
      for (int i = 0; i < 3; ++i)
#pragma unroll
        for (int j = 0; j < 3; ++j) {
          const float* bp = Wc + ((p + i) * 10 + (q + j)) * 12 + r0;
          float2 u0 = *(const float2*)bp;
          float2 u1 = *(const float2*)(bp + 2);
          const int ob = i * 9 + j * 3;
          acc0 += wA[ob + 0] * u0.x + wA[ob + 1] * u0.y + wA[ob + 2] * u1.x;
          acc1 += wB[ob + 0] * u0.y + wB[ob + 1] * u1.x + wB[ob + 2] * u1.y;
        }
      // z = bias + inv*conv_raw - inv*mu*(sum of weights)
      const float im = inv * mu;
      const float z0 = bv.x + inv * acc0 - im * SA;
      const float z1 = bv.y + inv * acc1 - im * SB;
      const float sg0 = __builtin_amdgcn_rcpf(1.f + __expf(-z0));
      const float sg1 = __builtin_amdgcn_rcpf(1.f + __expf(-z1));
      a0 += rv.x * (z0 * sg0);
      a1 += rv.y * (z1 * sg1);
      if (it < 7) {
        // write next state into the OTHER buffer: no pre-write barrier needed
        float* Wn = Wl[cur ^ 1];
        const int wi = ((p + 1) * 10 + q + 1) * 12 + r0 + 1;
        Wn[wi] = a0;
        Wn[wi + 1] = a1;
        float ls = a0 + a1;
        float lq = a0 * a0 + a1 * a1;
        ls = wave_sum(ls); lq = wave_sum(lq);
        const int par = (it & 1) * 8;
        if ((t & 63) == 0) { red[par + wv_ * 2] = ls; red[par + wv_ * 2 + 1] = lq; }
        __syncthreads();  // next-buf writes + reduction partials visible
        const float nS = red[par] + red[par + 2] + red[par + 4] + red[par + 6] + hS;
        const float nQ = red[par + 1] + red[par + 3] + red[par + 5] + red[par + 7] + hQ;
        mu = nS * 1e-3f;
        var = nQ * 1e-3f - mu * mu;
        inv = __builtin_amdgcn_rsqf(var + 1e-5f);
        cur ^= 1;
      }
    }
    const int baseo = ((b * 128 + gm0 + p) * 128 + (gn0 + q)) * 128 + (gk0 + r0);
    float2 ov; ov.x = a0; ov.y = a1;
    *(float2*)(out + baseo) = ov;
  }
}

extern "C" void kernel_launch(void* const* d_in, const int* in_sizes, int n_in,
                              void* d_out, int out_size, void* d_ws, size_t ws_size,
                              hipStream_t stream) {
  const float* weight = (const float*)d_in[0];
  const float* bias   = (const float*)d_in[1];
  const float* rscale = (const float*)d_in[2];
  const float* x      = (const float*)d_in[3];
  float* out = (float*)d_out;
  gridnet_kernel<<<dim3(16 * 16 * 16), dim3(256), 0, stream>>>(
      weight, bias, rscale, x, out);
}